// Round 1
// baseline (97.132 us; speedup 1.0000x reference)
//
#include <hip/hip_runtime.h>
#include <cstdint>
#include <cstddef>

// ---------------------------------------------------------------------------
// DeepIM: VAE (matvec chain) + 2-layer GAT on sparse adjacency.
// Key insight: GAT heads are rank-1 (Wh[i,:] = x_hat[i]*W), so attention
// logits are e[i,j] = leaky(c1*xh[i] + c2*xh[j]) and head outputs collapse
// to scalars t_h[i]. No N x N or N x 64 intermediates are ever materialized.
// ---------------------------------------------------------------------------

#define ACT_NONE 0
#define ACT_RELU 1
#define ACT_SIG  2

// y[r] = act( dot(W[r,:], x) + b[r] );  one block (256 thr) per row.
template<int ACT>
__global__ __launch_bounds__(256) void mv_kernel(const float* __restrict__ W,
    const float* __restrict__ x, const float* __restrict__ b,
    float* __restrict__ y, int C) {
  const int r = blockIdx.x;
  const float* row = W + (size_t)r * (size_t)C;
  float acc = 0.f;
  for (int c = threadIdx.x * 4; c < C; c += 256 * 4) {
    const float4 w4 = *reinterpret_cast<const float4*>(row + c);
    const float4 x4 = *reinterpret_cast<const float4*>(x + c);
    acc += w4.x * x4.x + w4.y * x4.y + w4.z * x4.z + w4.w * x4.w;
  }
  for (int off = 32; off; off >>= 1) acc += __shfl_down(acc, off);
  __shared__ float lds[4];
  if ((threadIdx.x & 63) == 0) lds[threadIdx.x >> 6] = acc;
  __syncthreads();
  if (threadIdx.x == 0) {
    float v = lds[0] + lds[1] + lds[2] + lds[3] + b[r];
    if (ACT == ACT_RELU) v = v > 0.f ? v : 0.f;
    if (ACT == ACT_SIG)  v = 1.f / (1.f + expf(-v));
    y[r] = v;
  }
}

// z = mu + eps * exp(0.5*logvar)
__global__ __launch_bounds__(256) void z_kernel(const float* __restrict__ mu,
    const float* __restrict__ logvar, const float* __restrict__ eps,
    float* __restrict__ z, int n) {
  const int i = blockIdx.x * 256 + threadIdx.x;
  if (i < n) z[i] = mu[i] + eps[i] * expf(0.5f * logvar[i]);
}

// Per-head scalars: c1[h]=W_h.a_h[:64], c2[h]=W_h.a_h[64:], d[h]=W_h.outW_h,
// plus oa0/oa1. consts layout: [c1(4), c2(4), d(4), oa0, oa1]
__global__ __launch_bounds__(256) void prep_kernel(const float* __restrict__ gw,
    const float* __restrict__ ga, const float* __restrict__ ow,
    const float* __restrict__ oa, float* __restrict__ consts) {
  const int t = threadIdx.x, h = t >> 6, k = t & 63;
  const float w = gw[h * 64 + k];
  float p1 = w * ga[h * 128 + k];
  float p2 = w * ga[h * 128 + 64 + k];
  float p3 = w * ow[h * 64 + k];
  for (int off = 32; off; off >>= 1) {
    p1 += __shfl_down(p1, off);
    p2 += __shfl_down(p2, off);
    p3 += __shfl_down(p3, off);
  }
  if (k == 0) { consts[h] = p1; consts[4 + h] = p2; consts[8 + h] = p3; }
  if (t == 0) { consts[12] = oa[0]; consts[13] = oa[1]; }
}

// Detect adjacency storage: flag=1 -> packed bytes (bool/uint8);
// flag=0 -> 4-byte elements (int32 0/1 OR float32 0.0/1.0 — same scan works).
__global__ __launch_bounds__(256) void sniff_kernel(const uint32_t* __restrict__ aw,
    int* __restrict__ flag) {
  int bad = 0;
  for (int i = threadIdx.x; i < 16384; i += 256) {
    const uint32_t w = aw[i];
    bad |= (w > 1u) && (w != 0x3F800000u);
  }
  __shared__ int lds[4];
  const unsigned long long m = __ballot(bad);
  if ((threadIdx.x & 63) == 0) lds[threadIdx.x >> 6] = (m != 0ull) ? 1 : 0;
  __syncthreads();
  if (threadIdx.x == 0) flag[0] = lds[0] | lds[1] | lds[2] | lds[3];
}

__global__ __launch_bounds__(256) void sum_kernel(const float* __restrict__ v,
    int n, float* __restrict__ out) {
  float a = 0.f;
  for (int i = threadIdx.x; i < n; i += 256) a += v[i];
  for (int off = 32; off; off >>= 1) a += __shfl_down(a, off);
  __shared__ float lds[4];
  if ((threadIdx.x & 63) == 0) lds[threadIdx.x >> 6] = a;
  __syncthreads();
  if (threadIdx.x == 0) out[0] = lds[0] + lds[1] + lds[2] + lds[3];
}

// 4 heads fused. One wave per row i. Online masked-softmax sums:
//   s_h = sum_j exp(leaky(c1_h*xh[i] + c2_h*xh[j])),  t_h = sum w*xh[j]
// then Wh2[i] = sum_h d_h * (t_h/s_h)   (uniform-attention fallback if row empty)
__global__ __launch_bounds__(256) void gat_heads_kernel(const void* __restrict__ adj,
    const float* __restrict__ xh, const float* __restrict__ consts,
    const int* __restrict__ flag, float* __restrict__ wh2,
    const float* __restrict__ sums) {
  const int lane = threadIdx.x & 63;
  const int i = blockIdx.x * 4 + (threadIdx.x >> 6);
  const float xi = xh[i];
  const float a0 = consts[0] * xi, a1 = consts[1] * xi,
              a2 = consts[2] * xi, a3 = consts[3] * xi;
  const float c20 = consts[4], c21 = consts[5], c22 = consts[6], c23 = consts[7];
  float s0 = 0, s1 = 0, s2 = 0, s3 = 0, t0 = 0, t1 = 0, t2 = 0, t3 = 0;

#define GACC(J) { const float xj = xh[(J)];                                     \
    float e0 = a0 + c20 * xj, e1 = a1 + c21 * xj,                               \
          e2 = a2 + c22 * xj, e3 = a3 + c23 * xj;                               \
    e0 = fmaxf(e0, 0.2f * e0); e1 = fmaxf(e1, 0.2f * e1);                       \
    e2 = fmaxf(e2, 0.2f * e2); e3 = fmaxf(e3, 0.2f * e3);                       \
    const float w0 = expf(e0), w1 = expf(e1), w2 = expf(e2), w3 = expf(e3);     \
    s0 += w0; s1 += w1; s2 += w2; s3 += w3;                                     \
    t0 += w0 * xj; t1 += w1 * xj; t2 += w2 * xj; t3 += w3 * xj; }

  if (*flag) {  // packed bytes: row = 4096 bytes
    const uint4* rw = reinterpret_cast<const uint4*>(
        (const uint8_t*)adj + (size_t)i * 4096u);
#pragma unroll
    for (int it = 0; it < 4; ++it) {
      const uint4 v = rw[it * 64 + lane];
      const uint32_t wv[4] = {v.x, v.y, v.z, v.w};
      const int jb = (it * 64 + lane) * 16;
#pragma unroll
      for (int w = 0; w < 4; ++w) {
        const uint32_t word = wv[w];
        if (!word) continue;
#pragma unroll
        for (int bb = 0; bb < 4; ++bb)
          if ((word >> (8 * bb)) & 0xffu) GACC(jb + w * 4 + bb)
      }
    }
  } else {      // 4-byte elements: row = 4096 words (int 0/1 or float 1.0f)
    const uint4* rw = reinterpret_cast<const uint4*>(
        (const uint32_t*)adj + (size_t)i * 4096u);
    for (int it = 0; it < 16; ++it) {
      const uint4 v = rw[it * 64 + lane];
      const uint32_t wv[4] = {v.x, v.y, v.z, v.w};
      const int jb = (it * 64 + lane) * 4;
#pragma unroll
      for (int w = 0; w < 4; ++w)
        if (wv[w]) GACC(jb + w)
    }
  }
#undef GACC
  for (int off = 32; off; off >>= 1) {
    s0 += __shfl_down(s0, off); s1 += __shfl_down(s1, off);
    s2 += __shfl_down(s2, off); s3 += __shfl_down(s3, off);
    t0 += __shfl_down(t0, off); t1 += __shfl_down(t1, off);
    t2 += __shfl_down(t2, off); t3 += __shfl_down(t3, off);
  }
  if (lane == 0) {
    const float d0 = consts[8], d1 = consts[9], d2 = consts[10], d3 = consts[11];
    float r0, r1, r2, r3;
    if (s0 != 0.f) { r0 = t0 / s0; r1 = t1 / s1; r2 = t2 / s2; r3 = t3 / s3; }
    else { r0 = r1 = r2 = r3 = sums[0] * (1.f / 4096.f); }  // empty row -> uniform att
    wh2[i] = d0 * r0 + d1 * r1 + d2 * r2 + d3 * r3;
  }
}

// Output GAT layer (f=1): e[i,j]=leaky(oa0*Wh2[i]+oa1*Wh2[j]); y=elu(att@Wh2)
__global__ __launch_bounds__(256) void gat_out_kernel(const void* __restrict__ adj,
    const float* __restrict__ wh2, const float* __restrict__ consts,
    const int* __restrict__ flag, float* __restrict__ yhat,
    const float* __restrict__ sums) {
  const int lane = threadIdx.x & 63;
  const int i = blockIdx.x * 4 + (threadIdx.x >> 6);
  const float oa1 = consts[13];
  const float al = consts[12] * wh2[i];
  float s = 0.f, t = 0.f;

#define GACC1(J) { const float wj = wh2[(J)];                                   \
    float e = al + oa1 * wj; e = fmaxf(e, 0.2f * e);                            \
    const float w = expf(e); s += w; t += w * wj; }

  if (*flag) {
    const uint4* rw = reinterpret_cast<const uint4*>(
        (const uint8_t*)adj + (size_t)i * 4096u);
#pragma unroll
    for (int it = 0; it < 4; ++it) {
      const uint4 v = rw[it * 64 + lane];
      const uint32_t wv[4] = {v.x, v.y, v.z, v.w};
      const int jb = (it * 64 + lane) * 16;
#pragma unroll
      for (int w = 0; w < 4; ++w) {
        const uint32_t word = wv[w];
        if (!word) continue;
#pragma unroll
        for (int bb = 0; bb < 4; ++bb)
          if ((word >> (8 * bb)) & 0xffu) GACC1(jb + w * 4 + bb)
      }
    }
  } else {
    const uint4* rw = reinterpret_cast<const uint4*>(
        (const uint32_t*)adj + (size_t)i * 4096u);
    for (int it = 0; it < 16; ++it) {
      const uint4 v = rw[it * 64 + lane];
      const uint32_t wv[4] = {v.x, v.y, v.z, v.w};
      const int jb = (it * 64 + lane) * 4;
#pragma unroll
      for (int w = 0; w < 4; ++w)
        if (wv[w]) GACC1(jb + w)
    }
  }
#undef GACC1
  for (int off = 32; off; off >>= 1) {
    s += __shfl_down(s, off);
    t += __shfl_down(t, off);
  }
  if (lane == 0) {
    const float v = (s != 0.f) ? (t / s) : sums[1] * (1.f / 4096.f);
    yhat[i] = v > 0.f ? v : expm1f(v);  // elu, alpha=1
  }
}

extern "C" void kernel_launch(void* const* d_in, const int* in_sizes, int n_in,
                              void* d_out, int out_size, void* d_ws, size_t ws_size,
                              hipStream_t stream) {
  const float* x      = (const float*)d_in[0];
  const float* eps    = (const float*)d_in[1];
  const void*  adj    = d_in[2];
  const float* enc_w1 = (const float*)d_in[3];
  const float* enc_b1 = (const float*)d_in[4];
  const float* enc_w2 = (const float*)d_in[5];
  const float* enc_b2 = (const float*)d_in[6];
  const float* enc_w3 = (const float*)d_in[7];
  const float* enc_b3 = (const float*)d_in[8];
  const float* enc_w4 = (const float*)d_in[9];
  const float* enc_b4 = (const float*)d_in[10];
  const float* dec_w1 = (const float*)d_in[11];
  const float* dec_b1 = (const float*)d_in[12];
  const float* dec_w2 = (const float*)d_in[13];
  const float* dec_b2 = (const float*)d_in[14];
  const float* dec_w3 = (const float*)d_in[15];
  const float* dec_b3 = (const float*)d_in[16];
  const float* gat_W  = (const float*)d_in[17];
  const float* gat_a  = (const float*)d_in[18];
  const float* out_W  = (const float*)d_in[19];
  const float* out_a  = (const float*)d_in[20];

  float* out    = (float*)d_out;
  float* xhat   = out;          // [0,4096)
  float* yhat   = out + 4096;   // [4096,8192)
  float* mu     = out + 8192;   // [8192,8704)
  float* logvar = out + 8704;   // [8704,9216)

  float* ws     = (float*)d_ws;
  float* h1     = ws;           // 1024
  float* h2     = ws + 1024;    // 1024
  float* z      = ws + 2048;    // 512
  float* h3     = ws + 2560;    // 1024
  float* h4     = ws + 3584;    // 1024
  float* wh2    = ws + 4608;    // 4096
  float* sums   = ws + 8704;    // [0]=sum(xhat), [1]=sum(wh2)
  float* consts = ws + 8708;    // 14 floats
  int*   flag   = (int*)(ws + 8724);

  prep_kernel<<<1, 256, 0, stream>>>(gat_W, gat_a, out_W, out_a, consts);
  sniff_kernel<<<1, 256, 0, stream>>>((const uint32_t*)adj, flag);

  // VAE encoder
  mv_kernel<ACT_RELU><<<1024, 256, 0, stream>>>(enc_w1, x,  enc_b1, h1, 4096);
  mv_kernel<ACT_RELU><<<1024, 256, 0, stream>>>(enc_w2, h1, enc_b2, h2, 1024);
  mv_kernel<ACT_NONE><<<512,  256, 0, stream>>>(enc_w3, h2, enc_b3, mu, 1024);
  mv_kernel<ACT_NONE><<<512,  256, 0, stream>>>(enc_w4, h2, enc_b4, logvar, 1024);
  z_kernel<<<2, 256, 0, stream>>>(mu, logvar, eps, z, 512);
  // VAE decoder
  mv_kernel<ACT_RELU><<<1024, 256, 0, stream>>>(dec_w1, z,  dec_b1, h3, 512);
  mv_kernel<ACT_RELU><<<1024, 256, 0, stream>>>(dec_w2, h3, dec_b2, h4, 1024);
  mv_kernel<ACT_SIG ><<<4096, 256, 0, stream>>>(dec_w3, h4, dec_b3, xhat, 1024);

  // GAT
  sum_kernel<<<1, 256, 0, stream>>>(xhat, 4096, &sums[0]);
  gat_heads_kernel<<<1024, 256, 0, stream>>>(adj, xhat, consts, flag, wh2, sums);
  sum_kernel<<<1, 256, 0, stream>>>(wh2, 4096, &sums[1]);
  gat_out_kernel<<<1024, 256, 0, stream>>>(adj, wh2, consts, flag, yhat, sums);
}

// Round 2
// 59.409 us; speedup vs baseline: 1.6350x; 1.6350x over previous
//
#include <hip/hip_runtime.h>
#include <cstdint>
#include <cstddef>

// ---------------------------------------------------------------------------
// DeepIM: VAE (matvec chain) + 2-layer GAT on sparse adjacency.
// GAT heads are rank-1 => attention logits e[i,j] = leaky(c1*xh[i]+c2*xh[j]);
// head outputs collapse to scalars. Adjacency (1% dense) is converted once to
// a 2 MB bitmap; both GAT layers scan the bitmap with ctz bit-iteration.
// ---------------------------------------------------------------------------

typedef unsigned long long u64;

#define ACT_NONE 0
#define ACT_RELU 1
#define ACT_SIG  2

// y[r] = act( dot(W[r,:], x) + b[r] );  one block (256 thr) per row.
template<int ACT>
__global__ __launch_bounds__(256) void mv_kernel(const float* __restrict__ W,
    const float* __restrict__ x, const float* __restrict__ b,
    float* __restrict__ y, int C) {
  const int r = blockIdx.x;
  const float* row = W + (size_t)r * (size_t)C;
  float acc = 0.f;
  for (int c = threadIdx.x * 4; c < C; c += 256 * 4) {
    const float4 w4 = *reinterpret_cast<const float4*>(row + c);
    const float4 x4 = *reinterpret_cast<const float4*>(x + c);
    acc += w4.x * x4.x + w4.y * x4.y + w4.z * x4.z + w4.w * x4.w;
  }
  for (int off = 32; off; off >>= 1) acc += __shfl_down(acc, off);
  __shared__ float lds[4];
  if ((threadIdx.x & 63) == 0) lds[threadIdx.x >> 6] = acc;
  __syncthreads();
  if (threadIdx.x == 0) {
    float v = lds[0] + lds[1] + lds[2] + lds[3] + b[r];
    if (ACT == ACT_RELU) v = v > 0.f ? v : 0.f;
    if (ACT == ACT_SIG)  v = 1.f / (1.f + expf(-v));
    y[r] = v;
  }
}

// mu (rows 0..511 via w3) and logvar (rows 512..1023 via w4) in one grid.
__global__ __launch_bounds__(256) void mulv_kernel(const float* __restrict__ w3,
    const float* __restrict__ b3, const float* __restrict__ w4,
    const float* __restrict__ b4, const float* __restrict__ h2,
    float* __restrict__ mu, float* __restrict__ logvar) {
  const int r = blockIdx.x;
  const bool is_mu = r < 512;
  const int rr = is_mu ? r : r - 512;
  const float* row = (is_mu ? w3 : w4) + (size_t)rr * 1024u;
  float acc = 0.f;
  {
    const int c = threadIdx.x * 4;
    const float4 w = *reinterpret_cast<const float4*>(row + c);
    const float4 x = *reinterpret_cast<const float4*>(h2 + c);
    acc = w.x * x.x + w.y * x.y + w.z * x.z + w.w * x.w;
  }
  for (int off = 32; off; off >>= 1) acc += __shfl_down(acc, off);
  __shared__ float lds[4];
  if ((threadIdx.x & 63) == 0) lds[threadIdx.x >> 6] = acc;
  __syncthreads();
  if (threadIdx.x == 0) {
    const float v = lds[0] + lds[1] + lds[2] + lds[3] + (is_mu ? b3[rr] : b4[rr]);
    (is_mu ? mu : logvar)[rr] = v;
  }
}

// dec layer 1 with z = mu + eps*exp(0.5*logvar) computed in LDS per block.
__global__ __launch_bounds__(256) void dec1_kernel(const float* __restrict__ W,
    const float* __restrict__ mu, const float* __restrict__ logvar,
    const float* __restrict__ eps, const float* __restrict__ b,
    float* __restrict__ y) {
  __shared__ float zs[512];
  for (int k = threadIdx.x; k < 512; k += 256)
    zs[k] = mu[k] + eps[k] * expf(0.5f * logvar[k]);
  __syncthreads();
  const int r = blockIdx.x;
  const float* row = W + (size_t)r * 512u;
  const int c = threadIdx.x * 2;
  const float2 w2 = *reinterpret_cast<const float2*>(row + c);
  float acc = w2.x * zs[c] + w2.y * zs[c + 1];
  for (int off = 32; off; off >>= 1) acc += __shfl_down(acc, off);
  __shared__ float lds[4];
  if ((threadIdx.x & 63) == 0) lds[threadIdx.x >> 6] = acc;
  __syncthreads();
  if (threadIdx.x == 0) {
    float v = lds[0] + lds[1] + lds[2] + lds[3] + b[r];
    y[r] = v > 0.f ? v : 0.f;
  }
}

// Per-head scalars + adjacency format sniff in one dispatch.
// consts layout: [c1(4), c2(4), d(4), oa0, oa1]
__global__ __launch_bounds__(256) void prep_sniff_kernel(const float* __restrict__ gw,
    const float* __restrict__ ga, const float* __restrict__ ow,
    const float* __restrict__ oa, const uint32_t* __restrict__ aw,
    float* __restrict__ consts, int* __restrict__ flag) {
  const int t = threadIdx.x, h = t >> 6, k = t & 63;
  const float w = gw[h * 64 + k];
  float p1 = w * ga[h * 128 + k];
  float p2 = w * ga[h * 128 + 64 + k];
  float p3 = w * ow[h * 64 + k];
  for (int off = 32; off; off >>= 1) {
    p1 += __shfl_down(p1, off);
    p2 += __shfl_down(p2, off);
    p3 += __shfl_down(p3, off);
  }
  if (k == 0) { consts[h] = p1; consts[4 + h] = p2; consts[8 + h] = p3; }
  if (t == 0) { consts[12] = oa[0]; consts[13] = oa[1]; }
  // sniff: any word not in {0,1,0x3F800000} proves packed-byte layout
  int bad = 0;
  for (int i = t; i < 16384; i += 256) {
    const uint32_t v = aw[i];
    bad |= (v > 1u) && (v != 0x3F800000u);
  }
  __shared__ int lds[4];
  const unsigned long long m = __ballot(bad);
  if ((t & 63) == 0) lds[t >> 6] = (m != 0ull) ? 1 : 0;
  __syncthreads();
  if (t == 0) flag[0] = lds[0] | lds[1] | lds[2] | lds[3];
}

// adj -> bitmap: bm[i*64+w] bit l == adj[i][w*64+l] != 0.  One block per row.
__global__ __launch_bounds__(256) void conv_kernel(const void* __restrict__ adj,
    const int* __restrict__ flag, u64* __restrict__ bm) {
  const int i = blockIdx.x;
  const int wv = threadIdx.x >> 6;
  const int lane = threadIdx.x & 63;
  if (*flag) {
    const uint8_t* row = (const uint8_t*)adj + (size_t)i * 4096u;
#pragma unroll
    for (int it = 0; it < 16; ++it) {
      const int w = wv * 16 + it;
      const u64 m = __ballot(row[w * 64 + lane] != 0);
      if (lane == 0) bm[(size_t)i * 64 + w] = m;
    }
  } else {
    const uint32_t* row = (const uint32_t*)adj + (size_t)i * 4096u;
#pragma unroll
    for (int it = 0; it < 16; ++it) {
      const int w = wv * 16 + it;
      const u64 m = __ballot(row[w * 64 + lane] != 0);
      if (lane == 0) bm[(size_t)i * 64 + w] = m;
    }
  }
}

// 4 heads fused, bitmap scan. One wave per row; lane = 64-bit word index.
__global__ __launch_bounds__(256) void gat_heads_bm(const u64* __restrict__ bm,
    const float* __restrict__ xh, const float* __restrict__ consts,
    float* __restrict__ wh2) {
  const int lane = threadIdx.x & 63;
  const int i = blockIdx.x * 4 + (threadIdx.x >> 6);
  const float xi = xh[i];
  const float a0 = consts[0] * xi, a1 = consts[1] * xi,
              a2 = consts[2] * xi, a3 = consts[3] * xi;
  const float c20 = consts[4], c21 = consts[5], c22 = consts[6], c23 = consts[7];
  float s0 = 0, s1 = 0, s2 = 0, s3 = 0, t0 = 0, t1 = 0, t2 = 0, t3 = 0;
  u64 m = bm[(size_t)i * 64 + lane];
  const int jb = lane * 64;
  while (m) {
    const int bpos = __builtin_ctzll(m);
    m &= m - 1;
    const float xj = xh[jb + bpos];
    float e0 = a0 + c20 * xj, e1 = a1 + c21 * xj,
          e2 = a2 + c22 * xj, e3 = a3 + c23 * xj;
    e0 = fmaxf(e0, 0.2f * e0); e1 = fmaxf(e1, 0.2f * e1);
    e2 = fmaxf(e2, 0.2f * e2); e3 = fmaxf(e3, 0.2f * e3);
    const float w0 = expf(e0), w1 = expf(e1), w2 = expf(e2), w3 = expf(e3);
    s0 += w0; s1 += w1; s2 += w2; s3 += w3;
    t0 += w0 * xj; t1 += w1 * xj; t2 += w2 * xj; t3 += w3 * xj;
  }
  for (int off = 1; off < 64; off <<= 1) {
    s0 += __shfl_xor(s0, off); s1 += __shfl_xor(s1, off);
    s2 += __shfl_xor(s2, off); s3 += __shfl_xor(s3, off);
    t0 += __shfl_xor(t0, off); t1 += __shfl_xor(t1, off);
    t2 += __shfl_xor(t2, off); t3 += __shfl_xor(t3, off);
  }
  float r0, r1, r2, r3;
  if (s0 != 0.f) { r0 = t0 / s0; r1 = t1 / s1; r2 = t2 / s2; r3 = t3 / s3; }
  else {  // empty row -> uniform attention over all nodes (mean of xh)
    float a = 0.f;
    for (int k = lane; k < 4096; k += 64) a += xh[k];
    for (int off = 1; off < 64; off <<= 1) a += __shfl_xor(a, off);
    r0 = r1 = r2 = r3 = a * (1.f / 4096.f);
  }
  if (lane == 0)
    wh2[i] = consts[8] * r0 + consts[9] * r1 + consts[10] * r2 + consts[11] * r3;
}

// Output GAT layer (f=1), bitmap scan. y = elu(att @ Wh2).
__global__ __launch_bounds__(256) void gat_out_bm(const u64* __restrict__ bm,
    const float* __restrict__ wh2, const float* __restrict__ consts,
    float* __restrict__ yhat) {
  const int lane = threadIdx.x & 63;
  const int i = blockIdx.x * 4 + (threadIdx.x >> 6);
  const float al = consts[12] * wh2[i];
  const float oa1 = consts[13];
  float s = 0.f, t = 0.f;
  u64 m = bm[(size_t)i * 64 + lane];
  const int jb = lane * 64;
  while (m) {
    const int bpos = __builtin_ctzll(m);
    m &= m - 1;
    const float wj = wh2[jb + bpos];
    float e = al + oa1 * wj;
    e = fmaxf(e, 0.2f * e);
    const float w = expf(e);
    s += w; t += w * wj;
  }
  for (int off = 1; off < 64; off <<= 1) {
    s += __shfl_xor(s, off);
    t += __shfl_xor(t, off);
  }
  float v;
  if (s != 0.f) v = t / s;
  else {
    float a = 0.f;
    for (int k = lane; k < 4096; k += 64) a += wh2[k];
    for (int off = 1; off < 64; off <<= 1) a += __shfl_xor(a, off);
    v = a * (1.f / 4096.f);
  }
  if (lane == 0) yhat[i] = v > 0.f ? v : expm1f(v);  // elu(alpha=1)
}

// ------------------- fallback (ws too small): direct adj scan ---------------
__global__ __launch_bounds__(256) void sum_kernel(const float* __restrict__ v,
    int n, float* __restrict__ out) {
  float a = 0.f;
  for (int i = threadIdx.x; i < n; i += 256) a += v[i];
  for (int off = 32; off; off >>= 1) a += __shfl_down(a, off);
  __shared__ float lds[4];
  if ((threadIdx.x & 63) == 0) lds[threadIdx.x >> 6] = a;
  __syncthreads();
  if (threadIdx.x == 0) out[0] = lds[0] + lds[1] + lds[2] + lds[3];
}

__global__ __launch_bounds__(256) void gat_heads_direct(const void* __restrict__ adj,
    const float* __restrict__ xh, const float* __restrict__ consts,
    const int* __restrict__ flag, float* __restrict__ wh2,
    const float* __restrict__ sums) {
  const int lane = threadIdx.x & 63;
  const int i = blockIdx.x * 4 + (threadIdx.x >> 6);
  const float xi = xh[i];
  const float a0 = consts[0] * xi, a1 = consts[1] * xi,
              a2 = consts[2] * xi, a3 = consts[3] * xi;
  const float c20 = consts[4], c21 = consts[5], c22 = consts[6], c23 = consts[7];
  float s0 = 0, s1 = 0, s2 = 0, s3 = 0, t0 = 0, t1 = 0, t2 = 0, t3 = 0;
#define GACC(J) { const float xj = xh[(J)];                                     \
    float e0 = a0 + c20 * xj, e1 = a1 + c21 * xj,                               \
          e2 = a2 + c22 * xj, e3 = a3 + c23 * xj;                               \
    e0 = fmaxf(e0, 0.2f * e0); e1 = fmaxf(e1, 0.2f * e1);                       \
    e2 = fmaxf(e2, 0.2f * e2); e3 = fmaxf(e3, 0.2f * e3);                       \
    const float w0 = expf(e0), w1 = expf(e1), w2 = expf(e2), w3 = expf(e3);     \
    s0 += w0; s1 += w1; s2 += w2; s3 += w3;                                     \
    t0 += w0 * xj; t1 += w1 * xj; t2 += w2 * xj; t3 += w3 * xj; }
  if (*flag) {
    const uint4* rw = reinterpret_cast<const uint4*>(
        (const uint8_t*)adj + (size_t)i * 4096u);
#pragma unroll
    for (int it = 0; it < 4; ++it) {
      const uint4 v = rw[it * 64 + lane];
      const uint32_t wv[4] = {v.x, v.y, v.z, v.w};
      const int jb = (it * 64 + lane) * 16;
#pragma unroll
      for (int w = 0; w < 4; ++w) {
        const uint32_t word = wv[w];
        if (!word) continue;
#pragma unroll
        for (int bb = 0; bb < 4; ++bb)
          if ((word >> (8 * bb)) & 0xffu) GACC(jb + w * 4 + bb)
      }
    }
  } else {
    const uint4* rw = reinterpret_cast<const uint4*>(
        (const uint32_t*)adj + (size_t)i * 4096u);
    for (int it = 0; it < 16; ++it) {
      const uint4 v = rw[it * 64 + lane];
      const uint32_t wv[4] = {v.x, v.y, v.z, v.w};
      const int jb = (it * 64 + lane) * 4;
#pragma unroll
      for (int w = 0; w < 4; ++w)
        if (wv[w]) GACC(jb + w)
    }
  }
#undef GACC
  for (int off = 32; off; off >>= 1) {
    s0 += __shfl_down(s0, off); s1 += __shfl_down(s1, off);
    s2 += __shfl_down(s2, off); s3 += __shfl_down(s3, off);
    t0 += __shfl_down(t0, off); t1 += __shfl_down(t1, off);
    t2 += __shfl_down(t2, off); t3 += __shfl_down(t3, off);
  }
  if (lane == 0) {
    float r0, r1, r2, r3;
    if (s0 != 0.f) { r0 = t0 / s0; r1 = t1 / s1; r2 = t2 / s2; r3 = t3 / s3; }
    else r0 = r1 = r2 = r3 = sums[0] * (1.f / 4096.f);
    wh2[i] = consts[8] * r0 + consts[9] * r1 + consts[10] * r2 + consts[11] * r3;
  }
}

__global__ __launch_bounds__(256) void gat_out_direct(const void* __restrict__ adj,
    const float* __restrict__ wh2, const float* __restrict__ consts,
    const int* __restrict__ flag, float* __restrict__ yhat,
    const float* __restrict__ sums) {
  const int lane = threadIdx.x & 63;
  const int i = blockIdx.x * 4 + (threadIdx.x >> 6);
  const float oa1 = consts[13];
  const float al = consts[12] * wh2[i];
  float s = 0.f, t = 0.f;
#define GACC1(J) { const float wj = wh2[(J)];                                   \
    float e = al + oa1 * wj; e = fmaxf(e, 0.2f * e);                            \
    const float w = expf(e); s += w; t += w * wj; }
  if (*flag) {
    const uint4* rw = reinterpret_cast<const uint4*>(
        (const uint8_t*)adj + (size_t)i * 4096u);
#pragma unroll
    for (int it = 0; it < 4; ++it) {
      const uint4 v = rw[it * 64 + lane];
      const uint32_t wv[4] = {v.x, v.y, v.z, v.w};
      const int jb = (it * 64 + lane) * 16;
#pragma unroll
      for (int w = 0; w < 4; ++w) {
        const uint32_t word = wv[w];
        if (!word) continue;
#pragma unroll
        for (int bb = 0; bb < 4; ++bb)
          if ((word >> (8 * bb)) & 0xffu) GACC1(jb + w * 4 + bb)
      }
    }
  } else {
    const uint4* rw = reinterpret_cast<const uint4*>(
        (const uint32_t*)adj + (size_t)i * 4096u);
    for (int it = 0; it < 16; ++it) {
      const uint4 v = rw[it * 64 + lane];
      const uint32_t wv[4] = {v.x, v.y, v.z, v.w};
      const int jb = (it * 64 + lane) * 4;
#pragma unroll
      for (int w = 0; w < 4; ++w)
        if (wv[w]) GACC1(jb + w)
    }
  }
#undef GACC1
  for (int off = 32; off; off >>= 1) {
    s += __shfl_down(s, off);
    t += __shfl_down(t, off);
  }
  if (lane == 0) {
    const float v = (s != 0.f) ? (t / s) : sums[1] * (1.f / 4096.f);
    yhat[i] = v > 0.f ? v : expm1f(v);
  }
}
// -----------------------------------------------------------------------------

extern "C" void kernel_launch(void* const* d_in, const int* in_sizes, int n_in,
                              void* d_out, int out_size, void* d_ws, size_t ws_size,
                              hipStream_t stream) {
  const float* x      = (const float*)d_in[0];
  const float* eps    = (const float*)d_in[1];
  const void*  adj    = d_in[2];
  const float* enc_w1 = (const float*)d_in[3];
  const float* enc_b1 = (const float*)d_in[4];
  const float* enc_w2 = (const float*)d_in[5];
  const float* enc_b2 = (const float*)d_in[6];
  const float* enc_w3 = (const float*)d_in[7];
  const float* enc_b3 = (const float*)d_in[8];
  const float* enc_w4 = (const float*)d_in[9];
  const float* enc_b4 = (const float*)d_in[10];
  const float* dec_w1 = (const float*)d_in[11];
  const float* dec_b1 = (const float*)d_in[12];
  const float* dec_w2 = (const float*)d_in[13];
  const float* dec_b2 = (const float*)d_in[14];
  const float* dec_w3 = (const float*)d_in[15];
  const float* dec_b3 = (const float*)d_in[16];
  const float* gat_W  = (const float*)d_in[17];
  const float* gat_a  = (const float*)d_in[18];
  const float* out_W  = (const float*)d_in[19];
  const float* out_a  = (const float*)d_in[20];

  float* out    = (float*)d_out;
  float* xhat   = out;          // [0,4096)
  float* yhat   = out + 4096;   // [4096,8192)
  float* mu     = out + 8192;   // [8192,8704)
  float* logvar = out + 8704;   // [8704,9216)

  const size_t BM_BYTES = (size_t)4096 * 64 * sizeof(u64);  // 2 MiB
  const bool fast = ws_size >= BM_BYTES + 64 * 1024;

  u64*   bm     = (u64*)d_ws;
  float* ws     = fast ? (float*)((char*)d_ws + BM_BYTES) : (float*)d_ws;
  float* h1     = ws;            // 1024
  float* h2     = ws + 1024;     // 1024
  float* h3     = ws + 2048;     // 1024
  float* h4     = ws + 3072;     // 1024
  float* wh2    = ws + 4096;     // 4096
  float* sums   = ws + 8192;     // 2 (fallback path only)
  float* consts = ws + 8208;     // 14
  int*   flag   = (int*)(ws + 8224);

  prep_sniff_kernel<<<1, 256, 0, stream>>>(gat_W, gat_a, out_W, out_a,
                                           (const uint32_t*)adj, consts, flag);
  if (fast)
    conv_kernel<<<4096, 256, 0, stream>>>(adj, flag, bm);

  // VAE encoder
  mv_kernel<ACT_RELU><<<1024, 256, 0, stream>>>(enc_w1, x,  enc_b1, h1, 4096);
  mv_kernel<ACT_RELU><<<1024, 256, 0, stream>>>(enc_w2, h1, enc_b2, h2, 1024);
  mulv_kernel<<<1024, 256, 0, stream>>>(enc_w3, enc_b3, enc_w4, enc_b4, h2, mu, logvar);
  // VAE decoder (z computed inside dec1)
  dec1_kernel<<<1024, 256, 0, stream>>>(dec_w1, mu, logvar, eps, dec_b1, h3);
  mv_kernel<ACT_RELU><<<1024, 256, 0, stream>>>(dec_w2, h3, dec_b2, h4, 1024);
  mv_kernel<ACT_SIG ><<<4096, 256, 0, stream>>>(dec_w3, h4, dec_b3, xhat, 1024);

  // GAT
  if (fast) {
    gat_heads_bm<<<1024, 256, 0, stream>>>(bm, xhat, consts, wh2);
    gat_out_bm<<<1024, 256, 0, stream>>>(bm, wh2, consts, yhat);
  } else {
    sum_kernel<<<1, 256, 0, stream>>>(xhat, 4096, &sums[0]);
    gat_heads_direct<<<1024, 256, 0, stream>>>(adj, xhat, consts, flag, wh2, sums);
    sum_kernel<<<1, 256, 0, stream>>>(wh2, 4096, &sums[1]);
    gat_out_direct<<<1024, 256, 0, stream>>>(adj, wh2, consts, flag, yhat, sums);
  }
}